// Round 12
// baseline (186.501 us; speedup 1.0000x reference)
//
#include <hip/hip_runtime.h>
#include <hip/hip_bf16.h>
#include <math.h>

// Problem constants
constexpr int B    = 2;
constexpr int C    = 64;
constexpr int H    = 224;
constexpr int W    = 224;
constexpr int Hp   = 226;   // padded
constexpr int Wp   = 226;
constexpr int OCO  = 18;
constexpr int OM   = 27;
constexpr int COUT = 64;
constexpr int HW   = H * W;         // 50176
constexpr int NPIX = B * HW;        // 100352
constexpr int CK   = C * 9;         // 576
constexpr int CPB  = 32;            // pixels per fused block

// k_prep sub-grid ranges
constexpr int PAD_BLKS = (HW / 32) * B;          // 3136
constexpr int BOR_N    = B * 900 * 8;            // 14400 border uint4-chunks
constexpr int BOR_BLKS = (BOR_N + 255) / 256;    // 57
constexpr int WA_BLKS  = (COUT * CK) / 256;      // 144
constexpr int WOM_BLKS = (32 * CK) / 256;        // 72

typedef short  bf16x8 __attribute__((ext_vector_type(8)));
typedef float  f32x4  __attribute__((ext_vector_type(4)));

__device__ inline unsigned short f2bf(float f) {
    union { float f; unsigned u; } v; v.f = f;
    unsigned r = v.u + 0x7FFF + ((v.u >> 16) & 1);   // RNE
    return (unsigned short)(r >> 16);
}
__device__ inline unsigned cvtpk(float a, float b) {
    __hip_bfloat162 h = __float22bfloat162_rn(make_float2(a, b));
    union { __hip_bfloat162 h; unsigned u; } cv; cv.h = h;
    return cv.u;
}
__device__ inline float blo(unsigned u) { union { unsigned u; float f; } c; c.u = u << 16; return c.f; }
__device__ inline float bhi(unsigned u) { union { unsigned u; float f; } c; c.u = u & 0xFFFF0000u; return c.f; }

// ---------------------------------------------------------------------------
// Kernel PREP: one launch for all preprocessing (independent sub-jobs).
// ---------------------------------------------------------------------------
__global__ __launch_bounds__(256) void k_prep(const float* __restrict__ x,
                                              unsigned short* __restrict__ xp,
                                              const float* __restrict__ wd,
                                              unsigned short* __restrict__ wA,
                                              const float* __restrict__ w_off,
                                              const float* __restrict__ w_msk,
                                              const float* __restrict__ b_off,
                                              const float* __restrict__ b_msk,
                                              unsigned short* __restrict__ womA,
                                              float* __restrict__ biasv) {
    __shared__ float tile[64][33];
    const int bx  = blockIdx.x;
    const int tid = threadIdx.x;

    if (bx < PAD_BLKS) {
        // ---- padT (float4 loads) ----
        const int b   = bx / (HW / 32);
        const int hw0 = (bx % (HW / 32)) * 32;
        const float* xb = x + (size_t)b * C * HW;
        {
            const int c  = tid >> 2;          // 0..63
            const int hq = (tid & 3) * 8;     // 0,8,16,24
            const float* src = xb + (size_t)c * HW + hw0 + hq;
            const float4 a0 = *reinterpret_cast<const float4*>(src);
            const float4 a1 = *reinterpret_cast<const float4*>(src + 4);
            tile[c][hq + 0] = a0.x; tile[c][hq + 1] = a0.y;
            tile[c][hq + 2] = a0.z; tile[c][hq + 3] = a0.w;
            tile[c][hq + 4] = a1.x; tile[c][hq + 5] = a1.y;
            tile[c][hq + 6] = a1.z; tile[c][hq + 7] = a1.w;
        }
        __syncthreads();
        unsigned short* xpb = xp + (size_t)b * Hp * Wp * C;
        const int l15 = tid & 15, hh = tid >> 4;
        const int c = l15 * 4;
#pragma unroll
        for (int half = 0; half < 2; ++half) {
            int hw = hw0 + half * 16 + hh;      // 32|W: stays in one image row
            int y = hw / W, xx = hw % W;
            float t0 = tile[c][half * 16 + hh],     t1 = tile[c + 1][half * 16 + hh];
            float t2 = tile[c + 2][half * 16 + hh], t3 = tile[c + 3][half * 16 + hh];
            *reinterpret_cast<uint2*>(xpb + ((size_t)(y + 1) * Wp + (xx + 1)) * C + c) =
                make_uint2(cvtpk(t0, t1), cvtpk(t2, t3));
        }
        return;
    }
    if (bx < PAD_BLKS + BOR_BLKS) {
        // ---- border zero ----
        int i = (bx - PAD_BLKS) * 256 + tid;
        if (i >= BOR_N) return;
        int chunk = i & 7;
        int cell  = (i >> 3) % 900;
        int b     = (i >> 3) / 900;
        int y, xx;
        if      (cell < 226) { y = 0;              xx = cell; }
        else if (cell < 452) { y = Hp - 1;         xx = cell - 226; }
        else if (cell < 676) { y = cell - 452 + 1; xx = 0; }
        else                 { y = cell - 676 + 1; xx = Wp - 1; }
        uint4 z = make_uint4(0u, 0u, 0u, 0u);
        *reinterpret_cast<uint4*>(xp + ((size_t)b * Hp * Wp + y * Wp + xx) * C + chunk * 8) = z;
        return;
    }
    if (bx < PAD_BLKS + BOR_BLKS + WA_BLKS) {
        // ---- wA ----
        int i  = (bx - PAD_BLKS - BOR_BLKS) * 256 + tid;   // < 36864
        int o  = i / CK;
        int kc = i % CK;
        int k  = kc >> 6;
        int c  = kc & 63;
        wA[i] = f2bf(wd[((size_t)o * C + c) * 9 + k]);
        return;
    }
    {
        // ---- womA + biasv ----
        int i = (bx - PAD_BLKS - BOR_BLKS - WA_BLKS) * 256 + tid;   // < 18432
        if (i < 32) biasv[i] = (i < OCO) ? b_off[i] : (i < OM) ? b_msk[i - OCO] : 0.f;
        int oc = i / CK;
        int kc = i % CK;
        int k  = kc >> 6;
        int c  = kc & 63;
        float v = (oc < OCO) ? w_off[((size_t)oc * C + c) * 9 + k]
                : (oc < OM)  ? w_msk[((size_t)(oc - OCO) * C + c) * 9 + k]
                             : 0.f;
        womA[i] = f2bf(v);
    }
}

// ---------------------------------------------------------------------------
// Fused kernel:
//   A: im2col -> imcol LDS (bf16, XOR-swizzled)
//   B: GEMM1 -> som LDS (offsets + sigmoid mask)
//   D: per-thread plan recompute (registers) + gather -> imcol (valT)
//   E: GEMM2 -> out
// LDS: 36864 + 3584 = 40448 B -> 4 blocks/CU (vs 3 with the old gplan LDS).
// Plan math is verbatim round-9 phase C, computed redundantly per thread.
// ---------------------------------------------------------------------------
__global__ __launch_bounds__(256, 4) void k_fused(const unsigned short* __restrict__ xp,
                                                  const unsigned short* __restrict__ womA,
                                                  const unsigned short* __restrict__ wA,
                                                  const float* __restrict__ biasv,
                                                  float* __restrict__ out) {
    __shared__ __align__(16) unsigned short imcol[CPB * CK];   // 36864 B (also valT)
    __shared__ float som[CPB][28];                             // 3584 B
    const int tid  = threadIdx.x;
    const int lane = tid & 63;
    const int wv   = tid >> 6;
    const int q    = lane >> 4;
    const int l15  = lane & 15;
    int bid = blockIdx.x;                        // nwg=3136, 3136%8==0
    bid = (bid & 7) * (gridDim.x >> 3) + (bid >> 3);
    const int pix0 = bid * CPB;
    const int bb   = pix0 / HW;                  // 32|HW: never spans batch
    const unsigned short* xb = xp + (size_t)bb * Hp * Wp * C;

    const int c0 = l15 * 4;

    // ---- Phase A: im2col (bf16 copy) ----
#pragma unroll
    for (int pi = 0; pi < 2; ++pi) {
        const int p_local = pi * 16 + wv * 4 + q;
        const int pix = pix0 + p_local;
        const int hw  = pix - bb * HW;
        const int y   = hw / W;
        const int xx  = hw % W;
        int wbase = p_local * (CK * 2) + l15 * 8;
        wbase ^= (p_local & 7) << 4;
#pragma unroll
        for (int k = 0; k < 9; ++k) {
            const int ky = k / 3, kx = k % 3;
            const uint2 v = *reinterpret_cast<const uint2*>(
                xb + ((size_t)(y + ky) * Wp + (xx + kx)) * C + c0);
            *reinterpret_cast<uint2*>(reinterpret_cast<char*>(imcol) + wbase + k * 128) = v;
        }
    }
    __syncthreads();

    // ---- Phase B: GEMM1, one 16x16 tile per wave: m=wv&1 (oc), n=wv>>1 (px) ----
    {
        f32x4 acc = {0.f, 0.f, 0.f, 0.f};
        const int m = wv & 1, n = wv >> 1;
        const unsigned short* a0 = womA + (size_t)(m * 16 + l15) * CK;
        const int row = n * 16 + l15;
#pragma unroll 3
        for (int ks = 0; ks < 18; ++ks) {
            int byte = row * (CK * 2) + ks * 64 + q * 16;
            byte ^= (row & 7) << 4;
            const bf16x8 bfv = *reinterpret_cast<const bf16x8*>(
                reinterpret_cast<const char*>(imcol) + byte);
            const bf16x8 af = *reinterpret_cast<const bf16x8*>(a0 + ks * 32 + q * 8);
            acc = __builtin_amdgcn_mfma_f32_16x16x32_bf16(af, bfv, acc, 0, 0, 0);
        }
        const int pp = n * 16 + l15;
#pragma unroll
        for (int r = 0; r < 4; ++r) {
            const int oc = m * 16 + q * 4 + r;
            if (oc < OM) {
                float v = acc[r] + biasv[oc];
                som[pp][oc] = (oc < OCO) ? v : 1.0f / (1.0f + __expf(-v));
            }
        }
    }
    __syncthreads();

    // ---- Phase D: per-thread plan recompute + gather -> valT (imcol) ----
#pragma unroll
    for (int pi = 0; pi < 2; ++pi) {
        const int p_local = pi * 16 + wv * 4 + q;
        const int pix = pix0 + p_local;
        const int hw  = pix - bb * HW;
        const int ho  = hw / W;
        const int wo  = hw - ho * W;
        int wbase = p_local * (CK * 2) + l15 * 8;
        wbase ^= (p_local & 7) << 4;

        int4   po[9];
        float4 pw[9];
#pragma unroll
        for (int k = 0; k < 9; ++k) {
            const int ky = k / 3, kx = k - (k / 3) * 3;
            const float dy = som[p_local][2 * k];
            const float dx = som[p_local][2 * k + 1];
            const float mm = som[p_local][OCO + k];
            const float py = dy + (float)(ho + ky - 1);
            const float px = dx + (float)(wo + kx - 1);
            const float fy = floorf(py), fx = floorf(px);
            const int   y0 = (int)fy,   x0 = (int)fx;
            const float wy1 = py - fy,  wx1 = px - fx;
            const float wy0 = 1.f - wy1, wx0 = 1.f - wx1;
            const bool iy0 = (y0 >= 0) & (y0 < H);
            const bool iy1 = (y0 + 1 >= 0) & (y0 + 1 < H);
            const bool ix0 = (x0 >= 0) & (x0 < W);
            const bool ix1 = (x0 + 1 >= 0) & (x0 + 1 < W);
            const int ya = min(max(y0 + 1, 0), Hp - 1);
            const int yb = min(max(y0 + 2, 0), Hp - 1);
            const int xa = min(max(x0 + 1, 0), Wp - 1);
            const int xc = min(max(x0 + 2, 0), Wp - 1);
            const int rA = ya * Wp, rB = yb * Wp;
            po[k] = make_int4((rA + xa) * C, (rA + xc) * C,
                              (rB + xa) * C, (rB + xc) * C);
            pw[k] = make_float4(
                wy0 * wx0 * mm * ((iy0 & ix0) ? 1.f : 0.f),
                wy0 * wx1 * mm * ((iy0 & ix1) ? 1.f : 0.f),
                wy1 * wx0 * mm * ((iy1 & ix0) ? 1.f : 0.f),
                wy1 * wx1 * mm * ((iy1 & ix1) ? 1.f : 0.f));
        }

        uint2 u00[9], u01[9], u10[9], u11[9];
#pragma unroll
        for (int k = 0; k < 9; ++k) {
            u00[k] = *reinterpret_cast<const uint2*>(xb + po[k].x + c0);
            u01[k] = *reinterpret_cast<const uint2*>(xb + po[k].y + c0);
            u10[k] = *reinterpret_cast<const uint2*>(xb + po[k].z + c0);
            u11[k] = *reinterpret_cast<const uint2*>(xb + po[k].w + c0);
        }
#pragma unroll
        for (int k = 0; k < 9; ++k) {
            const float4 wt = pw[k];
            const float s0 = wt.x * blo(u00[k].x) + wt.y * blo(u01[k].x) + wt.z * blo(u10[k].x) + wt.w * blo(u11[k].x);
            const float s1 = wt.x * bhi(u00[k].x) + wt.y * bhi(u01[k].x) + wt.z * bhi(u10[k].x) + wt.w * bhi(u11[k].x);
            const float s2 = wt.x * blo(u00[k].y) + wt.y * blo(u01[k].y) + wt.z * blo(u10[k].y) + wt.w * blo(u11[k].y);
            const float s3 = wt.x * bhi(u00[k].y) + wt.y * bhi(u01[k].y) + wt.z * bhi(u10[k].y) + wt.w * bhi(u11[k].y);
            *reinterpret_cast<uint2*>(reinterpret_cast<char*>(imcol) + wbase + k * 128) =
                make_uint2(cvtpk(s0, s1), cvtpk(s2, s3));
        }
    }
    __syncthreads();

    // ---- Phase E: GEMM2, wave = 16 o-rows x 32 px (2 n-tiles) ----
    f32x4 acc[2] = {{0.f,0.f,0.f,0.f},{0.f,0.f,0.f,0.f}};
    const unsigned short* wrow = wA + (size_t)(wv * 16 + l15) * CK;
#pragma unroll 3
    for (int ks = 0; ks < 18; ++ks) {
        const bf16x8 af = *reinterpret_cast<const bf16x8*>(wrow + ks * 32 + q * 8);
#pragma unroll
        for (int nt = 0; nt < 2; ++nt) {
            const int row = nt * 16 + l15;
            int byte = row * (CK * 2) + ks * 64 + q * 16;
            byte ^= (row & 7) << 4;
            const bf16x8 bfv = *reinterpret_cast<const bf16x8*>(
                reinterpret_cast<const char*>(imcol) + byte);
            acc[nt] = __builtin_amdgcn_mfma_f32_16x16x32_bf16(af, bfv, acc[nt], 0, 0, 0);
        }
    }

    // ---- Store ----
    const int o0 = wv * 16 + q * 4;
#pragma unroll
    for (int nt = 0; nt < 2; ++nt) {
        const int pixn = pix0 + nt * 16 + l15;
        const int hw   = pixn - bb * HW;
#pragma unroll
        for (int r = 0; r < 4; ++r)
            out[((size_t)bb * COUT + o0 + r) * HW + hw] = acc[nt][r];
    }
}

// ---------------------------------------------------------------------------
extern "C" void kernel_launch(void* const* d_in, const int* in_sizes, int n_in,
                              void* d_out, int out_size, void* d_ws, size_t ws_size,
                              hipStream_t stream) {
    const float* x     = (const float*)d_in[0];
    const float* w_off = (const float*)d_in[1];
    const float* b_off = (const float*)d_in[2];
    const float* w_msk = (const float*)d_in[3];
    const float* b_msk = (const float*)d_in[4];
    const float* w_def = (const float*)d_in[5];
    float* out = (float*)d_out;

    unsigned short* xpadT = (unsigned short*)d_ws;            // B*Hp*Wp*C bf16
    float* biasv = (float*)(xpadT + (size_t)B * Hp * Wp * C); // 32 floats
    unsigned short* wA   = (unsigned short*)(biasv + 32);     // 64*576 bf16
    unsigned short* womA = wA + (size_t)COUT * CK;            // 32*576 bf16

    k_prep<<<PAD_BLKS + BOR_BLKS + WA_BLKS + WOM_BLKS, 256, 0, stream>>>(
        x, xpadT, w_def, wA, w_off, w_msk, b_off, b_msk, womA, biasv);
    k_fused<<<NPIX / CPB, 256, 0, stream>>>(xpadT, womA, wA, biasv, out);
}